// Round 3
// baseline (254.315 us; speedup 1.0000x reference)
//
#include <hip/hip_runtime.h>

// TSAdaptivePatcher: x[64][64][8192] f32, mask[64][8192] i32
// PATCH=STRIDE=16 -> n_patches=512, non-overlapping => pure (c,p)-chunk transpose
// out = [ patches: 64*512*1024 f32 ][ padding_mask: 64*512 f32 ]
//
// v4: direct no-LDS transpose — copy-identical READS, scattered full-line WRITES.
//  One block per (b, c) row: reads x[b][c][0:8192] fully sequentially
//  (1 KiB contiguous per wave-instr, 32 KiB per block = perfect DRAM streaks),
//  writes 512 chunks of 64 B (one (p,c) chunk each, full cache sectors) at
//  4 KiB stride. No LDS, no barriers, 0 shared mem -> 32 waves/CU occupancy
//  (2x v1..v3), 8 loads in flight per thread.
//  Rationale: v1-v3 (contiguous writes + strided reads via LDS) are all
//  structure-invariant at ~3.9 TB/s; this flips the scatter onto the
//  latency-insensitive store path and makes the load path copy-identical.

typedef float f4 __attribute__((ext_vector_type(4)));

constexpr int Bb  = 64;
constexpr int Cc  = 64;
constexpr int Ss  = 8192;
constexpr int NP  = 512;     // 1 + (8192-16)/16
constexpr size_t PATCH_ELEMS = (size_t)Bb * NP * Cc * 16; // 33,554,432

__global__ __launch_bounds__(256) void ts_patcher_kernel(
    const float* __restrict__ x,
    const int*   __restrict__ mask,
    float*       __restrict__ out)
{
    const int t   = threadIdx.x;
    const int blk = blockIdx.x;
    const int b   = blk >> 6;            // batch
    const int c   = blk & 63;            // channel (this block's input row)

    const float* xr = x + ((size_t)b * Cc + c) * Ss;

    // float4-unit base of out chunk (b, p=0, c, j=0):
    //   float idx = (b*512 + p)*1024 + c*16 + j  ->  f4 idx = b*131072 + p*256 + c*4 + jj
    f4* ob = (f4*)out + (size_t)b * 131072 + (size_t)c * 4;

    // ---- read 32 KiB row sequentially (8 x 4 KiB block-iters) ----
    f4 v[8];
#pragma unroll
    for (int i = 0; i < 8; ++i)
        v[i] = *(const f4*)(xr + (size_t)i * 1024 + t * 4);

    // ---- write 64 B chunks: lane t covers patch p = i*64 + t/4, float4 jj = t&3 ----
#pragma unroll
    for (int i = 0; i < 8; ++i) {
        const int p = i * 64 + (t >> 2);
        ob[(size_t)p * 256 + (t & 3)] = v[i];
    }

    // ---- fused padding mask: done once per batch by the c==0 blocks ----
    if (c == 0) {
        const int4* mb = (const int4*)(mask + (size_t)b * Ss);
#pragma unroll
        for (int k = 0; k < 2; ++k) {
            const int p = 2 * t + k;                   // 2 patches per thread
            int4 a = mb[p * 4 + 0], d = mb[p * 4 + 1];
            int4 e = mb[p * 4 + 2], f = mb[p * 4 + 3];
            int s = a.x + a.y + a.z + a.w
                  + d.x + d.y + d.z + d.w
                  + e.x + e.y + e.z + e.w
                  + f.x + f.y + f.z + f.w;
            // mean >= 0.5  <=>  sum >= 8  (mask values in {0,1})
            out[PATCH_ELEMS + (size_t)b * NP + p] = (s >= 8) ? 1.0f : 0.0f;
        }
    }
}

extern "C" void kernel_launch(void* const* d_in, const int* in_sizes, int n_in,
                              void* d_out, int out_size, void* d_ws, size_t ws_size,
                              hipStream_t stream) {
    const float* x    = (const float*)d_in[0];
    const int*   mask = (const int*)d_in[1];
    float*       out  = (float*)d_out;

    const int blocks = Bb * Cc;          // 4096: one per (b, c) input row
    ts_patcher_kernel<<<blocks, 256, 0, stream>>>(x, mask, out);
}

// Round 5
// 228.900 us; speedup vs baseline: 1.1110x; 1.1110x over previous
//
#include <hip/hip_runtime.h>

// TSAdaptivePatcher: x[64][64][8192] f32, mask[64][8192] i32
// PATCH=STRIDE=16 -> n_patches=512, non-overlapping => pure (c,p)-chunk transpose
// out = [ patches: 64*512*1024 f32 ][ padding_mask: 64*512 f32 ]
//
// v5b = v1 (best structure: LDS-staged tile transpose, contiguous writes)
//       + NONTEMPORAL output stores (single-variable change; ext_vector_type
//       pointer form — HIP float4 class type is rejected by the builtin).
//  Evidence: v4's counters showed FETCH_SIZE=66.6MB for the 134MB input ->
//  half of x is L3-resident at kernel start. Regular stores write-allocate,
//  evicting x mid-kernel and polluting L3 with never-re-read output lines.
//  NT stores stream the output past cache, preserving L3 for the read side.
//  Phase 1 (global->LDS): per wave-instr = 2 contiguous 512B segments.
//  Phase 2 (LDS->global): per wave-instr = 1 KB contiguous NT store.
//  LDS stride 132 (=128+4): inherent 1KB/128B bank minimum, no excess conflicts.

typedef float f4 __attribute__((ext_vector_type(4)));

constexpr int Bb  = 64;
constexpr int Cc  = 64;
constexpr int Ss  = 8192;
constexpr int NP  = 512;     // 1 + (8192-16)/16
constexpr int PT  = 8;       // patches per tile
constexpr int ROWF = PT * 16;          // 128 floats of each c-row per tile
constexpr int LSTRIDE = ROWF + 4;      // 132, pad to rotate banks per c-row
constexpr size_t PATCH_ELEMS = (size_t)Bb * NP * Cc * 16; // 33,554,432

__global__ __launch_bounds__(256) void ts_patcher_kernel(
    const float* __restrict__ x,
    const int*   __restrict__ mask,
    float*       __restrict__ out)
{
    __shared__ float lds[Cc * LSTRIDE];   // 64*132*4 = 33792 B

    const int t   = threadIdx.x;
    const int blk = blockIdx.x;
    const int b   = blk >> 6;             // / (NP/PT) = /64
    const int P0  = (blk & 63) * PT;      // first patch of tile

    const float* xb = x + (size_t)b * Cc * Ss + P0 * 16;

    // ---- Phase 1: global -> LDS (linear tile sweep) ----
    // iter i covers tile floats [i*1024, i*1024+1024) = c-rows [i*8, i*8+8)
    {
        const int c0  = t >> 5;           // t/32: row within the 8-row group
        const int col = (t & 31) * 4;     // 0..124
#pragma unroll
        for (int i = 0; i < 8; ++i) {
            const int c = i * 8 + c0;
            const f4 v = *(const f4*)(xb + (size_t)c * Ss + col);
            *(f4*)(&lds[c * LSTRIDE + col]) = v;
        }
    }

    __syncthreads();

    // ---- Phase 2: LDS -> global (8 contiguous 4 KB output rows = 32 KB) ----
    // iter i writes output row (b, P0+i); thread t covers floats [4t, 4t+4)
    // NONTEMPORAL: output is never re-read by this kernel -> bypass cache
    // allocate, keep L3 serving the x read stream.
    {
        float* otile = out + ((size_t)(b * NP + P0) * (Cc * 16));
        const int c = t >> 2;             // t/4
        const int j = (t & 3) * 4;
#pragma unroll
        for (int i = 0; i < 8; ++i) {
            const f4 v = *(const f4*)(&lds[c * LSTRIDE + i * 16 + j]);
            __builtin_nontemporal_store(v, (f4*)(otile + (size_t)i * 1024 + t * 4));
        }
    }

    // ---- Fused padding mask: threads 0..7, one patch each ----
    if (t < PT) {
        const int p = P0 + t;
        const int4* m = (const int4*)(mask + (size_t)b * Ss + p * 16);
        int4 a = m[0], d = m[1], e = m[2], f = m[3];
        int s = a.x + a.y + a.z + a.w
              + d.x + d.y + d.z + d.w
              + e.x + e.y + e.z + e.w
              + f.x + f.y + f.z + f.w;
        // mean >= 0.5  <=>  sum >= 8  (mask values in {0,1})
        out[PATCH_ELEMS + (size_t)b * NP + p] = (s >= 8) ? 1.0f : 0.0f;
    }
}

extern "C" void kernel_launch(void* const* d_in, const int* in_sizes, int n_in,
                              void* d_out, int out_size, void* d_ws, size_t ws_size,
                              hipStream_t stream) {
    const float* x    = (const float*)d_in[0];
    const int*   mask = (const int*)d_in[1];
    float*       out  = (float*)d_out;

    const int blocks = Bb * (NP / PT);   // 64 * 64 = 4096
    ts_patcher_kernel<<<blocks, 256, 0, stream>>>(x, mask, out);
}